// Round 4
// baseline (341.354 us; speedup 1.0000x reference)
//
#include <hip/hip_runtime.h>
#include <hip/hip_bf16.h>

typedef __attribute__((ext_vector_type(8))) __bf16 bf16x8;
typedef __attribute__((ext_vector_type(8))) short short8;
typedef __attribute__((ext_vector_type(4))) float f32x4;
typedef __attribute__((ext_vector_type(4))) unsigned int uint4v;

#define KS 66   // LDS row stride in shorts = 33 dwords === 1 (mod 32): near-conflict-free frag reads
#define LOG2E 1.44269504088896340736f

// pack two fp32 -> two bf16 (lo in low short), round-half-up
__device__ __forceinline__ unsigned pack2bf(float lo, float hi) {
    unsigned a = __builtin_bit_cast(unsigned, lo) + 0x8000u;
    unsigned b = __builtin_bit_cast(unsigned, hi) + 0x8000u;
    return __builtin_amdgcn_perm(b, a, 0x07060302u);
}

__device__ __forceinline__ bf16x8 ldfrag(const short* p) {
    short8 s = *reinterpret_cast<const short8*>(p);
    return __builtin_bit_cast(bf16x8, s);
}

// S^T formulation (R3) + 512-thread blocks (128 Q rows) + double-buffered K/V LDS
// with a 1-barrier/iter pipeline: write LDS[p] -> barrier -> issue loads(kt+1) ->
// compute(LDS[p]). Loads are consumed only in the NEXT write phase, so their
// latency is hidden behind a full compute phase and the pre-barrier vmcnt(0)
// drain is already satisfied.
__global__ __launch_bounds__(512, 6) void vfa_kernel(
    const float* __restrict__ qv, const float* __restrict__ kv, const float* __restrict__ vv,
    const float* __restrict__ eq, const float* __restrict__ ek, const float* __restrict__ ev,
    const float* __restrict__ scale_p, float* __restrict__ out)
{
    constexpr int H = 16, Dh = 64, ENC = 128, SV = 1536;
    // longest-first: seqlens desc {1152,1008,864,720,640,560,480,400}
    constexpr int SS_CUM[9] = {0,144,272,384,480,560,640,704,768};
    constexpr int SEQL[8] = {1152,1008,864,720,640,560,480,400};
    constexpr int QTN[8]  = {9,8,7,6,5,5,4,4};          // 128-row Q tiles
    constexpr int OB[8]   = {2080,4096,3232,5104,0,1120,640,1680};
    constexpr int BB[8]   = {1,5,3,7,0,4,2,6};
    constexpr int ISUM[8] = {512,512,512,512,0,0,0,0};

    __shared__ __align__(16) short smem[2][2*64*KS];    // [p][ K(64xKS) | V^T(64xKS) ] = 33792 B

    const int bid = blockIdx.x;
    int ss = 0;
    #pragma unroll
    for (int i = 1; i < 8; ++i) ss += (bid >= SS_CUM[i]) ? 1 : 0;
    const int seqlen   = SEQL[ss];
    const int nqt      = QTN[ss];
    const int b        = BB[ss];
    const int isum     = ISUM[ss];
    const int out_base = OB[ss];
    const int local    = bid - SS_CUM[ss];
    const int head     = local / nqt;
    const int qt       = local - head * nqt;

    const int tid  = threadIdx.x;
    const int wave = tid >> 6;          // 0..7
    const int lane = tid & 63;
    const int quad = lane >> 4;
    const int l15  = lane & 15;

    const float qmul = scale_p[0] * LOG2E;

    // ---- Q fragments (B-operand layout: n=l15, k=quad*8+j), kept in regs ----
    const int qrow = qt*128 + wave*16 + l15;            // qt==0 <=> encoder rows (ENC=128)
    const float* qrp;
    if (qrow < ENC) qrp = eq + ((b*ENC + qrow)*H + head)*Dh;
    else            qrp = qv + (((b*SV + isum) + (qrow - ENC))*H + head)*Dh;
    bf16x8 qfrag[2];
    #pragma unroll
    for (int f = 0; f < 2; ++f) {
        const float* p = qrp + f*32 + quad*8;
        float4 a = *reinterpret_cast<const float4*>(p);
        float4 c = *reinterpret_cast<const float4*>(p + 4);
        uint4v u;
        u[0] = pack2bf(a.x*qmul, a.y*qmul);
        u[1] = pack2bf(a.z*qmul, a.w*qmul);
        u[2] = pack2bf(c.x*qmul, c.y*qmul);
        u[3] = pack2bf(c.z*qmul, c.w*qmul);
        qfrag[f] = __builtin_bit_cast(bf16x8, u);
    }

    f32x4 acc[4];                       // O^T: acc[dt] row d=dt*16+quad*4+r, col q=l15
    #pragma unroll
    for (int dt = 0; dt < 4; ++dt) acc[dt] = {0.f,0.f,0.f,0.f};
    float m_s = -INFINITY, l_s = 0.f;   // per-lane softmax state (q = l15)

    const int kl = tid >> 3;            // 0..63: staged key
    const int g  = tid & 7;             // dim group: d in [g*8, g*8+8)
    const int nkt = (seqlen + 63) >> 6;
    const int src_base = l15 + ((quad & 1) << 5);

    float4 kf[2], vf[2];                // pipeline regs: raw fp32, converted in write phase
    auto load_tile = [&](int kt) {
        const int kr = kt*64 + kl;
        const float *krow, *vrow;
        if (kr < ENC) {
            krow = ek + ((b*ENC + kr)*H + head)*Dh;
            vrow = ev + ((b*ENC + kr)*H + head)*Dh;
        } else {
            const int row = (b*SV + isum) + (kr - ENC);
            krow = kv + (row*H + head)*Dh;
            vrow = vv + (row*H + head)*Dh;
        }
        kf[0] = *reinterpret_cast<const float4*>(krow + g*8);
        kf[1] = *reinterpret_cast<const float4*>(krow + g*8 + 4);
        vf[0] = *reinterpret_cast<const float4*>(vrow + g*8);
        vf[1] = *reinterpret_cast<const float4*>(vrow + g*8 + 4);
    };

    load_tile(0);
    int p = 0;

    for (int kt = 0; kt < nkt; ++kt) {
        short* kb = smem[p];
        short* vb = smem[p] + 64*KS;

        // ---- write phase: regs (tile kt) -> LDS[p]; waits the in-flight loads here ----
        {
            uint4v kp;
            kp[0] = pack2bf(kf[0].x, kf[0].y);
            kp[1] = pack2bf(kf[0].z, kf[0].w);
            kp[2] = pack2bf(kf[1].x, kf[1].y);
            kp[3] = pack2bf(kf[1].z, kf[1].w);
            *reinterpret_cast<uint4v*>(&kb[kl*KS + g*8]) = kp;    // 2-way banks: free
            float e[8] = {vf[0].x, vf[0].y, vf[0].z, vf[0].w,
                          vf[1].x, vf[1].y, vf[1].z, vf[1].w};
            #pragma unroll
            for (int i = 0; i < 8; ++i) {
                unsigned u = __builtin_bit_cast(unsigned, e[i]) + 0x8000u;
                vb[(g*8 + i)*KS + kl] = (short)(u >> 16);         // 2-way banks: free
            }
        }
        __syncthreads();                // single barrier per iteration

        if (kt + 1 < nkt) load_tile(kt + 1);   // in flight during compute; waited next write phase

        const int rem  = seqlen - kt*64;
        const int nsub = (rem >= 64) ? 4 : (rem >> 4);   // seqlens are multiples of 16

        // ---- QK^T -> S^T ----
        float s[4][4];
        #pragma unroll
        for (int sub = 0; sub < 4; ++sub) {
            if (sub < nsub) {
                const short* kr0 = &kb[(sub*16 + l15)*KS + quad*8];
                f32x4 sv = {0.f,0.f,0.f,0.f};
                sv = __builtin_amdgcn_mfma_f32_16x16x32_bf16(ldfrag(kr0),      qfrag[0], sv, 0,0,0);
                sv = __builtin_amdgcn_mfma_f32_16x16x32_bf16(ldfrag(kr0 + 32), qfrag[1], sv, 0,0,0);
                #pragma unroll
                for (int r = 0; r < 4; ++r) s[sub][r] = sv[r];
            } else {
                #pragma unroll
                for (int r = 0; r < 4; ++r) s[sub][r] = -INFINITY;
            }
        }

        // ---- online softmax (per-lane scalar state) ----
        float mx = s[0][0];
        #pragma unroll
        for (int sub = 0; sub < 4; ++sub)
            #pragma unroll
            for (int r = 0; r < 4; ++r) mx = fmaxf(mx, s[sub][r]);
        mx = fmaxf(mx, __shfl_xor(mx, 16, 64));
        mx = fmaxf(mx, __shfl_xor(mx, 32, 64));
        const float mn = fmaxf(m_s, mx);
        const float alpha = __builtin_amdgcn_exp2f(m_s - mn);
        m_s = mn;
        #pragma unroll
        for (int dt = 0; dt < 4; ++dt)
            #pragma unroll
            for (int r = 0; r < 4; ++r) acc[dt][r] *= alpha;

        float rs = 0.f;
        unsigned pk[4][2];
        #pragma unroll
        for (int sub = 0; sub < 4; ++sub) {
            float p0 = __builtin_amdgcn_exp2f(s[sub][0] - mn);
            float p1 = __builtin_amdgcn_exp2f(s[sub][1] - mn);
            float p2 = __builtin_amdgcn_exp2f(s[sub][2] - mn);
            float p3 = __builtin_amdgcn_exp2f(s[sub][3] - mn);
            rs += (p0 + p1) + (p2 + p3);
            pk[sub][0] = pack2bf(p0, p1);
            pk[sub][1] = pack2bf(p2, p3);
        }
        rs += __shfl_xor(rs, 16, 64);
        rs += __shfl_xor(rs, 32, 64);
        l_s = l_s * alpha + rs;

        // ---- PV: O^T += V^T x P^T ; P^T B-frag via bpermute ----
        #pragma unroll
        for (int kstep = 0; kstep < 2; ++kstep) {
            if (kstep == 0 || nsub > 2) {
                uint4v pf;
                #pragma unroll
                for (int pp = 0; pp < 4; ++pp) {
                    const int sl = src_base + ((pp >> 1) << 4);
                    int va = __shfl((int)pk[kstep*2 + 0][pp & 1], sl, 64);
                    int vb2 = __shfl((int)pk[kstep*2 + 1][pp & 1], sl, 64);
                    pf[pp] = (quad & 2) ? (unsigned)vb2 : (unsigned)va;
                }
                bf16x8 pfr = __builtin_bit_cast(bf16x8, pf);
                #pragma unroll
                for (int dt = 0; dt < 4; ++dt) {
                    bf16x8 vfr = ldfrag(&vb[(dt*16 + l15)*KS + kstep*32 + quad*8]);
                    acc[dt] = __builtin_amdgcn_mfma_f32_16x16x32_bf16(vfr, pfr, acc[dt], 0,0,0);
                }
            }
        }
        p ^= 1;
    }

    // ---- epilogue: normalize, transpose via LDS, coalesced f32 stores ----
    __syncthreads();                    // all waves done with K/V buffers
    float* tbuf = reinterpret_cast<float*>(&smem[0][0]);    // [128][66] f32 = 33792 B (exact fit)
    const float inv = 1.0f / l_s;
    #pragma unroll
    for (int dt = 0; dt < 4; ++dt)
        #pragma unroll
        for (int r = 0; r < 4; ++r)
            tbuf[(wave*16 + l15)*66 + dt*16 + quad*4 + r] = acc[dt][r] * inv;
    __syncthreads();

    const int rowl = tid >> 2;          // 0..127
    const int seg  = tid & 3;
    const int grow = qt*128 + rowl;
    if (grow < seqlen) {
        float* orow = out + (size_t)(out_base + grow)*(H*Dh) + head*Dh + seg*16;
        const float* tr = tbuf + rowl*66 + seg*16;
        #pragma unroll
        for (int c = 0; c < 4; ++c)
            *reinterpret_cast<float4*>(orow + c*4) = *reinterpret_cast<const float4*>(tr + c*4);
    }
}

extern "C" void kernel_launch(void* const* d_in, const int* in_sizes, int n_in,
                              void* d_out, int out_size, void* d_ws, size_t ws_size,
                              hipStream_t stream) {
    const float* q     = (const float*)d_in[0];
    const float* k     = (const float*)d_in[1];
    const float* v     = (const float*)d_in[2];
    const float* eq    = (const float*)d_in[3];
    const float* ek    = (const float*)d_in[4];
    const float* ev    = (const float*)d_in[5];
    const float* scale = (const float*)d_in[11];
    float* out = (float*)d_out;

    vfa_kernel<<<dim3(768), dim3(512), 0, stream>>>(q, k, v, eq, ek, ev, scale, out);
}